// Round 5
// baseline (286.104 us; speedup 1.0000x reference)
//
#include <hip/hip_runtime.h>
#include <cstddef>

namespace {

constexpr int kB = 32, kT = 512, kD = 64, kP = 16, kNW = 63, kDM = 512;
constexpr int kRows = kD * kNW + kT;     // 4544 output rows per batch
constexpr int kNBT = kB * kD;            // 2048 temporal blocks
constexpr int kNBF = kB * (kT / 16);     // 1024 feature blocks (16 rows each)

typedef float f32x4 __attribute__((ext_vector_type(4)));

__device__ __forceinline__ float rl(float v, int lane) {
    return __int_as_float(__builtin_amdgcn_readlane(__float_as_int(v), lane));
}

__device__ __forceinline__ void ntstore4(float* p, float a, float b, float c, float d) {
    f32x4 v = {a, b, c, d};
    __builtin_nontemporal_store(v, (f32x4*)p);
}

__device__ __forceinline__ float dot16(const float* w16, const float4* q) {
    float a0 = w16[0]  * q[0].x + w16[1]  * q[0].y;
    float a1 = w16[2]  * q[0].z + w16[3]  * q[0].w;
    float a2 = w16[4]  * q[1].x + w16[5]  * q[1].y;
    float a3 = w16[6]  * q[1].z + w16[7]  * q[1].w;
    a0 += w16[8]  * q[2].x + w16[9]  * q[2].y;
    a1 += w16[10] * q[2].z + w16[11] * q[2].w;
    a2 += w16[12] * q[3].x + w16[13] * q[3].y;
    a3 += w16[14] * q[3].z + w16[15] * q[3].w;
    return (a0 + a1) + (a2 + a3);
}

__device__ __forceinline__ float dot8(const float* v8, const float4* q) {
    float a0 = v8[0] * q[0].x + v8[1] * q[0].y;
    float a1 = v8[2] * q[0].z + v8[3] * q[0].w;
    float a2 = v8[4] * q[1].x + v8[5] * q[1].y;
    float a3 = v8[6] * q[1].z + v8[7] * q[1].w;
    return (a0 + a1) + (a2 + a3);
}

__global__ __launch_bounds__(512)
void patch_embed(const float* __restrict__ x,
                 const float* __restrict__ Wt,
                 const float* __restrict__ bt,
                 const float* __restrict__ Wd,
                 const float* __restrict__ bd,
                 float* __restrict__ out)
{
    const int tid  = threadIdx.x;
    const int lane = tid & 63;
    int blk = blockIdx.x;

    if (blk < kNBT) {
        // ---- temporal: out[b, d*63+w, 4m4+c] = sum_p x[b,8w+p,d]*Wt[4m4+c,p] + bt
        __shared__ float xs[kT];
        const int b  = blk >> 6;
        const int d  = blk & (kD - 1);
        const int rg = tid >> 7;          // row group: w ≡ rg (mod 4)
        const int m4 = tid & 127;
        const int mbase = m4 * 4;

        xs[tid] = x[(b * kT + tid) * kD + d];

        // weights for 4 consecutive channels: 64 regs
        float4 q[4][4];
        #pragma unroll
        for (int c = 0; c < 4; ++c) {
            const float4* wp = (const float4*)(Wt + (mbase + c) * kP);
            q[c][0] = wp[0]; q[c][1] = wp[1]; q[c][2] = wp[2]; q[c][3] = wp[3];
        }
        const float4 bias = *(const float4*)(bt + mbase);
        __syncthreads();

        // lane l holds column elements 8l..8l+7 in regs
        float4 xa = ((const float4*)xs)[lane * 2];
        float4 xb = ((const float4*)xs)[lane * 2 + 1];
        float xc[8] = {xa.x, xa.y, xa.z, xa.w, xb.x, xb.y, xb.z, xb.w};

        size_t obase = (size_t)b * kRows * kDM + (size_t)(d * kNW) * kDM + mbase;
        for (int w = rg; w < kNW; w += 4) {
            float win[kP];
            #pragma unroll
            for (int j = 0; j < 8; ++j) {
                win[j]     = rl(xc[j], w);       // elements 8w..8w+7
                win[8 + j] = rl(xc[j], w + 1);   // elements 8w+8..8w+15
            }
            ntstore4(out + obase + (size_t)w * kDM,
                     bias.x + dot16(win, q[0]),
                     bias.y + dot16(win, q[1]),
                     bias.z + dot16(win, q[2]),
                     bias.w + dot16(win, q[3]));
        }
    } else {
        // ---- feature: out[b, 4032+t, 4m4+c] = sum_d x[b,t,d]*Wd[4m4+c,d] + bd
        blk -= kNBT;
        const int b  = blk >> 5;
        const int t0 = (blk & 31) * 16;
        const int rowg = tid >> 7;        // rows 4*rowg .. 4*rowg+3 of the 16-chunk
        const int m4   = tid & 127;
        const int mbase = m4 * 4;

        // stage the 16x64 x-chunk: lane l holds flat elements [16l, 16l+16)
        const float4* xbase = (const float4*)(x + (size_t)(b * kT + t0) * kD);
        float xf[16];
        #pragma unroll
        for (int i = 0; i < 4; ++i) {
            float4 v = xbase[lane * 4 + i];
            xf[4*i+0] = v.x; xf[4*i+1] = v.y; xf[4*i+2] = v.z; xf[4*i+3] = v.w;
        }

        const float4 bias = *(const float4*)(bd + mbase);
        float4 acc[4] = {{0,0,0,0},{0,0,0,0},{0,0,0,0},{0,0,0,0}};

        // d chunked by 8: weights 4ch x 8d = 32 regs live
        #pragma unroll
        for (int dc = 0; dc < 8; ++dc) {
            float4 wq[4][2];
            #pragma unroll
            for (int c = 0; c < 4; ++c) {
                const float4* wp = (const float4*)(Wd + (size_t)(mbase + c) * kD + dc * 8);
                wq[c][0] = wp[0]; wq[c][1] = wp[1];
            }
            #pragma unroll
            for (int rr = 0; rr < 4; ++rr) {
                const int r = 4 * rowg + rr;                  // row in chunk
                const int srcl = 4 * r + (dc >> 1);           // lane holding d-slice
                const int rbase = (dc & 1) * 8;               // reg offset in that lane
                float xv[8];
                #pragma unroll
                for (int j = 0; j < 8; ++j)
                    xv[j] = rl(xf[rbase + j], srcl);
                acc[rr].x += dot8(xv, wq[0]);
                acc[rr].y += dot8(xv, wq[1]);
                acc[rr].z += dot8(xv, wq[2]);
                acc[rr].w += dot8(xv, wq[3]);
            }
        }

        size_t obase = (size_t)b * kRows * kDM
                     + (size_t)(kD * kNW + t0) * kDM + mbase;
        #pragma unroll
        for (int rr = 0; rr < 4; ++rr) {
            const int r = 4 * rowg + rr;
            ntstore4(out + obase + (size_t)r * kDM,
                     acc[rr].x + bias.x,
                     acc[rr].y + bias.y,
                     acc[rr].z + bias.z,
                     acc[rr].w + bias.w);
        }
    }
}

} // namespace

extern "C" void kernel_launch(void* const* d_in, const int* in_sizes, int n_in,
                              void* d_out, int out_size, void* d_ws, size_t ws_size,
                              hipStream_t stream) {
    const float* x  = (const float*)d_in[0];
    const float* Wt = (const float*)d_in[1];
    const float* bt = (const float*)d_in[2];
    const float* Wd = (const float*)d_in[3];
    const float* bd = (const float*)d_in[4];
    float* out = (float*)d_out;

    dim3 grid(kNBT + kNBF);
    dim3 block(512);
    hipLaunchKernelGGL(patch_embed, grid, block, 0, stream, x, Wt, bt, Wd, bd, out);
}

// Round 6
// 93.511 us; speedup vs baseline: 3.0596x; 3.0596x over previous
//
#include <hip/hip_runtime.h>
#include <cstddef>

namespace {

constexpr int kB = 32, kT = 512, kD = 64, kP = 16, kNW = 63, kDM = 512;
constexpr int kRows = kD * kNW + kT;     // 4544 output rows per batch

typedef float f32x4 __attribute__((ext_vector_type(4)));

__device__ __forceinline__ float rl(float v, int lane) {
    return __int_as_float(__builtin_amdgcn_readlane(__float_as_int(v), lane));
}

__device__ __forceinline__ void ntstore4(float* p, float a, float b, float c, float d) {
    f32x4 v = {a, b, c, d};
    __builtin_nontemporal_store(v, (f32x4*)p);
}

__device__ __forceinline__ float dot16(const float* w16, const float4* q) {
    float a0 = w16[0]  * q[0].x + w16[1]  * q[0].y;
    float a1 = w16[2]  * q[0].z + w16[3]  * q[0].w;
    float a2 = w16[4]  * q[1].x + w16[5]  * q[1].y;
    float a3 = w16[6]  * q[1].z + w16[7]  * q[1].w;
    a0 += w16[8]  * q[2].x + w16[9]  * q[2].y;
    a1 += w16[10] * q[2].z + w16[11] * q[2].w;
    a2 += w16[12] * q[3].x + w16[13] * q[3].y;
    a3 += w16[14] * q[3].z + w16[15] * q[3].w;
    return (a0 + a1) + (a2 + a3);
}

// ---- temporal: out[b, d*63+w, 4m4+c] = sum_p x[b,8w+p,d]*Wt[4m4+c,p] + bt
// grid 2048 = (b,d); block 256; thread = 4 channels x ~32 rows
__global__ __launch_bounds__(256)
void temporal_k(const float* __restrict__ x,
                const float* __restrict__ Wt,
                const float* __restrict__ bt,
                float* __restrict__ out)
{
    __shared__ float xs[kT];
    const int tid  = threadIdx.x;
    const int lane = tid & 63;
    const int b = blockIdx.x >> 6;
    const int d = blockIdx.x & (kD - 1);
    const int rg    = tid >> 7;           // w ≡ rg (mod 2), uniform per wave
    const int mbase = (tid & 127) * 4;

    xs[tid]       = x[(b * kT + tid) * kD + d];
    xs[tid + 256] = x[(b * kT + tid + 256) * kD + d];

    float4 q[4][4];
    #pragma unroll
    for (int c = 0; c < 4; ++c) {
        const float4* wp = (const float4*)(Wt + (mbase + c) * kP);
        q[c][0] = wp[0]; q[c][1] = wp[1]; q[c][2] = wp[2]; q[c][3] = wp[3];
    }
    const float4 bias = *(const float4*)(bt + mbase);
    __syncthreads();

    // lane l holds column elements 8l..8l+7 in regs
    float4 xa = ((const float4*)xs)[lane * 2];
    float4 xb = ((const float4*)xs)[lane * 2 + 1];
    float xc8[8] = {xa.x, xa.y, xa.z, xa.w, xb.x, xb.y, xb.z, xb.w};

    size_t obase = (size_t)b * kRows * kDM + (size_t)(d * kNW) * kDM + mbase;
    for (int w = rg; w < kNW; w += 2) {
        float win[kP];
        #pragma unroll
        for (int j = 0; j < 8; ++j) {
            win[j]     = rl(xc8[j], w);       // x elements 8w..8w+7
            win[8 + j] = rl(xc8[j], w + 1);   // x elements 8w+8..8w+15
        }
        ntstore4(out + obase + (size_t)w * kDM,
                 bias.x + dot16(win, q[0]),
                 bias.y + dot16(win, q[1]),
                 bias.z + dot16(win, q[2]),
                 bias.w + dot16(win, q[3]));
    }
}

// ---- feature: out[b, 4032+t, 4m4+c] = sum_d x[b,t,d]*Wd[4m4+c,d] + bd
// grid 1024 = (b, 16-row chunk); block 256; thread = 4 channels x 8 rows
__global__ __launch_bounds__(256)
void feature_k(const float* __restrict__ x,
               const float* __restrict__ Wd,
               const float* __restrict__ bd,
               float* __restrict__ out)
{
    const int tid  = threadIdx.x;
    const int lane = tid & 63;
    const int b  = blockIdx.x >> 5;
    const int t0 = (blockIdx.x & 31) * 16;
    const int rowg  = tid >> 7;           // rows 8*rowg..8*rowg+7, uniform per wave
    const int mbase = (tid & 127) * 4;

    // stage the 16x64 x-chunk in lane regs: lane l holds flat [16l, 16l+16)
    const float4* xbase = (const float4*)(x + (size_t)(b * kT + t0) * kD);
    float xf[16];
    #pragma unroll
    for (int i = 0; i < 4; ++i) {
        float4 v = xbase[lane * 4 + i];
        xf[4*i+0] = v.x; xf[4*i+1] = v.y; xf[4*i+2] = v.z; xf[4*i+3] = v.w;
    }

    float4 acc[8];
    #pragma unroll
    for (int r = 0; r < 8; ++r) { acc[r].x = 0.f; acc[r].y = 0.f; acc[r].z = 0.f; acc[r].w = 0.f; }

    // d in 4 chunks of 16; weights (4ch x 16d = 64 regs) live for one chunk only
    #pragma unroll 1
    for (int dc = 0; dc < 4; ++dc) {
        float4 wq[4][4];
        #pragma unroll
        for (int c = 0; c < 4; ++c) {
            const float4* wp = (const float4*)(Wd + (size_t)(mbase + c) * kD + dc * 16);
            wq[c][0] = wp[0]; wq[c][1] = wp[1]; wq[c][2] = wp[2]; wq[c][3] = wp[3];
        }
        #pragma unroll
        for (int r8 = 0; r8 < 8; ++r8) {
            const int srcl = 4 * (rowg * 8 + r8) + dc;   // lane holding this row's d-chunk
            float xv[16];
            #pragma unroll
            for (int j = 0; j < 16; ++j)
                xv[j] = rl(xf[j], srcl);                 // x[row, 16dc+j]
            acc[r8].x += dot16(xv, wq[0]);
            acc[r8].y += dot16(xv, wq[1]);
            acc[r8].z += dot16(xv, wq[2]);
            acc[r8].w += dot16(xv, wq[3]);
        }
    }

    const float4 bias = *(const float4*)(bd + mbase);
    size_t obase = (size_t)b * kRows * kDM
                 + (size_t)(kD * kNW + t0 + rowg * 8) * kDM + mbase;
    #pragma unroll
    for (int r8 = 0; r8 < 8; ++r8) {
        ntstore4(out + obase + (size_t)r8 * kDM,
                 acc[r8].x + bias.x,
                 acc[r8].y + bias.y,
                 acc[r8].z + bias.z,
                 acc[r8].w + bias.w);
    }
}

} // namespace

extern "C" void kernel_launch(void* const* d_in, const int* in_sizes, int n_in,
                              void* d_out, int out_size, void* d_ws, size_t ws_size,
                              hipStream_t stream) {
    const float* x  = (const float*)d_in[0];
    const float* Wt = (const float*)d_in[1];
    const float* bt = (const float*)d_in[2];
    const float* Wd = (const float*)d_in[3];
    const float* bd = (const float*)d_in[4];
    float* out = (float*)d_out;

    hipLaunchKernelGGL(temporal_k, dim3(kB * kD),      dim3(256), 0, stream, x, Wt, bt, out);
    hipLaunchKernelGGL(feature_k,  dim3(kB * (kT/16)), dim3(256), 0, stream, x, Wd, bd, out);
}

// Round 7
// 92.630 us; speedup vs baseline: 3.0887x; 1.0095x over previous
//
#include <hip/hip_runtime.h>
#include <cstddef>

namespace {

constexpr int kB = 32, kT = 512, kD = 64, kP = 16, kNW = 63, kDM = 512;
constexpr int kRows = kD * kNW + kT;     // 4544 output rows per batch

typedef float f32x4 __attribute__((ext_vector_type(4)));

__device__ __forceinline__ float rl(float v, int lane) {
    return __int_as_float(__builtin_amdgcn_readlane(__float_as_int(v), lane));
}

// Plain (L2-allocating) 16B store — A/B vs round 6's nontemporal version.
__device__ __forceinline__ void store4(float* p, float a, float b, float c, float d) {
    f32x4 v = {a, b, c, d};
    *(f32x4*)p = v;
}

__device__ __forceinline__ float dot16(const float* w16, const float4* q) {
    float a0 = w16[0]  * q[0].x + w16[1]  * q[0].y;
    float a1 = w16[2]  * q[0].z + w16[3]  * q[0].w;
    float a2 = w16[4]  * q[1].x + w16[5]  * q[1].y;
    float a3 = w16[6]  * q[1].z + w16[7]  * q[1].w;
    a0 += w16[8]  * q[2].x + w16[9]  * q[2].y;
    a1 += w16[10] * q[2].z + w16[11] * q[2].w;
    a2 += w16[12] * q[3].x + w16[13] * q[3].y;
    a3 += w16[14] * q[3].z + w16[15] * q[3].w;
    return (a0 + a1) + (a2 + a3);
}

// ---- temporal: out[b, d*63+w, 4m4+c] = sum_p x[b,8w+p,d]*Wt[4m4+c,p] + bt
__global__ __launch_bounds__(256)
void temporal_k(const float* __restrict__ x,
                const float* __restrict__ Wt,
                const float* __restrict__ bt,
                float* __restrict__ out)
{
    __shared__ float xs[kT];
    const int tid  = threadIdx.x;
    const int lane = tid & 63;
    const int b = blockIdx.x >> 6;
    const int d = blockIdx.x & (kD - 1);
    const int rg    = tid >> 7;           // w ≡ rg (mod 2), uniform per wave
    const int mbase = (tid & 127) * 4;

    xs[tid]       = x[(b * kT + tid) * kD + d];
    xs[tid + 256] = x[(b * kT + tid + 256) * kD + d];

    float4 q[4][4];
    #pragma unroll
    for (int c = 0; c < 4; ++c) {
        const float4* wp = (const float4*)(Wt + (mbase + c) * kP);
        q[c][0] = wp[0]; q[c][1] = wp[1]; q[c][2] = wp[2]; q[c][3] = wp[3];
    }
    const float4 bias = *(const float4*)(bt + mbase);
    __syncthreads();

    // lane l holds column elements 8l..8l+7 in regs
    float4 xa = ((const float4*)xs)[lane * 2];
    float4 xb = ((const float4*)xs)[lane * 2 + 1];
    float xc8[8] = {xa.x, xa.y, xa.z, xa.w, xb.x, xb.y, xb.z, xb.w};

    size_t obase = (size_t)b * kRows * kDM + (size_t)(d * kNW) * kDM + mbase;
    for (int w = rg; w < kNW; w += 2) {
        float win[kP];
        #pragma unroll
        for (int j = 0; j < 8; ++j) {
            win[j]     = rl(xc8[j], w);       // x elements 8w..8w+7
            win[8 + j] = rl(xc8[j], w + 1);   // x elements 8w+8..8w+15
        }
        store4(out + obase + (size_t)w * kDM,
               bias.x + dot16(win, q[0]),
               bias.y + dot16(win, q[1]),
               bias.z + dot16(win, q[2]),
               bias.w + dot16(win, q[3]));
    }
}

// ---- feature: out[b, 4032+t, 4m4+c] = sum_d x[b,t,d]*Wd[4m4+c,d] + bd
__global__ __launch_bounds__(256)
void feature_k(const float* __restrict__ x,
               const float* __restrict__ Wd,
               const float* __restrict__ bd,
               float* __restrict__ out)
{
    const int tid  = threadIdx.x;
    const int lane = tid & 63;
    const int b  = blockIdx.x >> 5;
    const int t0 = (blockIdx.x & 31) * 16;
    const int rowg  = tid >> 7;           // rows 8*rowg..8*rowg+7, uniform per wave
    const int mbase = (tid & 127) * 4;

    // stage the 16x64 x-chunk in lane regs: lane l holds flat [16l, 16l+16)
    const float4* xbase = (const float4*)(x + (size_t)(b * kT + t0) * kD);
    float xf[16];
    #pragma unroll
    for (int i = 0; i < 4; ++i) {
        float4 v = xbase[lane * 4 + i];
        xf[4*i+0] = v.x; xf[4*i+1] = v.y; xf[4*i+2] = v.z; xf[4*i+3] = v.w;
    }

    float4 acc[8];
    #pragma unroll
    for (int r = 0; r < 8; ++r) { acc[r].x = 0.f; acc[r].y = 0.f; acc[r].z = 0.f; acc[r].w = 0.f; }

    // d in 4 chunks of 16; weights (4ch x 16d = 64 regs) live for one chunk only
    #pragma unroll 1
    for (int dc = 0; dc < 4; ++dc) {
        float4 wq[4][4];
        #pragma unroll
        for (int c = 0; c < 4; ++c) {
            const float4* wp = (const float4*)(Wd + (size_t)(mbase + c) * kD + dc * 16);
            wq[c][0] = wp[0]; wq[c][1] = wp[1]; wq[c][2] = wp[2]; wq[c][3] = wp[3];
        }
        #pragma unroll
        for (int r8 = 0; r8 < 8; ++r8) {
            const int srcl = 4 * (rowg * 8 + r8) + dc;   // lane holding this row's d-chunk
            float xv[16];
            #pragma unroll
            for (int j = 0; j < 16; ++j)
                xv[j] = rl(xf[j], srcl);                 // x[row, 16dc+j]
            acc[r8].x += dot16(xv, wq[0]);
            acc[r8].y += dot16(xv, wq[1]);
            acc[r8].z += dot16(xv, wq[2]);
            acc[r8].w += dot16(xv, wq[3]);
        }
    }

    const float4 bias = *(const float4*)(bd + mbase);
    size_t obase = (size_t)b * kRows * kDM
                 + (size_t)(kD * kNW + t0 + rowg * 8) * kDM + mbase;
    #pragma unroll
    for (int r8 = 0; r8 < 8; ++r8) {
        store4(out + obase + (size_t)r8 * kDM,
               acc[r8].x + bias.x,
               acc[r8].y + bias.y,
               acc[r8].z + bias.z,
               acc[r8].w + bias.w);
    }
}

} // namespace

extern "C" void kernel_launch(void* const* d_in, const int* in_sizes, int n_in,
                              void* d_out, int out_size, void* d_ws, size_t ws_size,
                              hipStream_t stream) {
    const float* x  = (const float*)d_in[0];
    const float* Wt = (const float*)d_in[1];
    const float* bt = (const float*)d_in[2];
    const float* Wd = (const float*)d_in[3];
    const float* bd = (const float*)d_in[4];
    float* out = (float*)d_out;

    hipLaunchKernelGGL(temporal_k, dim3(kB * kD),      dim3(256), 0, stream, x, Wt, bt, out);
    hipLaunchKernelGGL(feature_k,  dim3(kB * (kT/16)), dim3(256), 0, stream, x, Wd, bd, out);
}

// Round 8
// 91.422 us; speedup vs baseline: 3.1295x; 1.0132x over previous
//
#include <hip/hip_runtime.h>
#include <cstddef>

namespace {

constexpr int kB = 32, kT = 512, kD = 64, kP = 16, kNW = 63, kDM = 512;
constexpr int kRows = kD * kNW + kT;     // 4544 output rows per batch

typedef float f32x4 __attribute__((ext_vector_type(4)));

__device__ __forceinline__ float rl(float v, int lane) {
    return __int_as_float(__builtin_amdgcn_readlane(__float_as_int(v), lane));
}

__device__ __forceinline__ float dot16(const float* w16, const float4* q) {
    float a0 = w16[0]  * q[0].x + w16[1]  * q[0].y;
    float a1 = w16[2]  * q[0].z + w16[3]  * q[0].w;
    float a2 = w16[4]  * q[1].x + w16[5]  * q[1].y;
    float a3 = w16[6]  * q[1].z + w16[7]  * q[1].w;
    a0 += w16[8]  * q[2].x + w16[9]  * q[2].y;
    a1 += w16[10] * q[2].z + w16[11] * q[2].w;
    a2 += w16[12] * q[3].x + w16[13] * q[3].y;
    a3 += w16[14] * q[3].z + w16[15] * q[3].w;
    return (a0 + a1) + (a2 + a3);
}

// ---- temporal: out[b, d*63+w, 4c..] = sum_p x[b,8w+p,d]*Wt[.,p] + bt
// Burst-store version: each wave computes 4 rows, then fires 4 dwordx4
// stores back-to-back -> 4 stores in flight per wave (vs 1 before).
__global__ __launch_bounds__(256)
void temporal_k(const float* __restrict__ x,
                const float* __restrict__ Wt,
                const float* __restrict__ bt,
                float* __restrict__ out)
{
    __shared__ float xs[kT];
    const int tid  = threadIdx.x;
    const int lane = tid & 63;
    const int wave = tid >> 6;            // 0..3
    const int b = blockIdx.x >> 6;
    const int d = blockIdx.x & (kD - 1);

    // wave pair: half 0 -> rows 0..31, half 1 -> rows 32..62
    // within pair: wave owns 256 channels; thread owns 4 channels
    const int half  = wave >> 1;
    const int mbase = (wave & 1) * 256 + lane * 4;

    xs[tid]       = x[(b * kT + tid) * kD + d];
    xs[tid + 256] = x[(b * kT + tid + 256) * kD + d];

    float4 q[4][4];
    #pragma unroll
    for (int c = 0; c < 4; ++c) {
        const float4* wp = (const float4*)(Wt + (mbase + c) * kP);
        q[c][0] = wp[0]; q[c][1] = wp[1]; q[c][2] = wp[2]; q[c][3] = wp[3];
    }
    const float4 bias = *(const float4*)(bt + mbase);
    __syncthreads();

    // lane l holds column elements 8l..8l+7 in regs
    float4 xa = ((const float4*)xs)[lane * 2];
    float4 xb = ((const float4*)xs)[lane * 2 + 1];
    float xc8[8] = {xa.x, xa.y, xa.z, xa.w, xb.x, xb.y, xb.z, xb.w};

    size_t obase = (size_t)b * kRows * kDM + (size_t)(d * kNW) * kDM + mbase;
    const int wbeg = half * 32;
    const int wcnt = half ? 31 : 32;      // rows 32..62 = 31 rows

    for (int i = 0; i < 32; i += 4) {     // 8 bursts of 4 rows
        const int w0 = wbeg + i;

        // x elements 8*w0 .. 8*w0+47 (rows w0..w0+3 need 16 each, overlap 8)
        float win[48];
        #pragma unroll
        for (int g = 0; g < 6; ++g) {
            const int src = (w0 + g) > 63 ? 63 : (w0 + g);  // clamp (garbage only feeds dropped rows)
            #pragma unroll
            for (int j = 0; j < 8; ++j)
                win[g * 8 + j] = rl(xc8[j], src);
        }

        // compute 4 rows into fresh regs
        f32x4 o[4];
        #pragma unroll
        for (int r = 0; r < 4; ++r) {
            const float* wp = win + 8 * r;
            o[r].x = bias.x + dot16(wp, q[0]);
            o[r].y = bias.y + dot16(wp, q[1]);
            o[r].z = bias.z + dot16(wp, q[2]);
            o[r].w = bias.w + dot16(wp, q[3]);
        }

        // burst the stores back-to-back
        #pragma unroll
        for (int r = 0; r < 4; ++r) {
            if (i + r < wcnt)
                *(f32x4*)(out + obase + (size_t)(w0 + r) * kDM) = o[r];
        }
    }
}

// ---- feature: out[b, 4032+t, 4m4+c] = sum_d x[b,t,d]*Wd[4m4+c,d] + bd
// already burst-structured: 8 dwordx4 stores at the end
__global__ __launch_bounds__(256)
void feature_k(const float* __restrict__ x,
               const float* __restrict__ Wd,
               const float* __restrict__ bd,
               float* __restrict__ out)
{
    const int tid  = threadIdx.x;
    const int lane = tid & 63;
    const int b  = blockIdx.x >> 5;
    const int t0 = (blockIdx.x & 31) * 16;
    const int rowg  = tid >> 7;           // rows 8*rowg..8*rowg+7, uniform per wave
    const int mbase = (tid & 127) * 4;

    // stage the 16x64 x-chunk in lane regs: lane l holds flat [16l, 16l+16)
    const float4* xbase = (const float4*)(x + (size_t)(b * kT + t0) * kD);
    float xf[16];
    #pragma unroll
    for (int i = 0; i < 4; ++i) {
        float4 v = xbase[lane * 4 + i];
        xf[4*i+0] = v.x; xf[4*i+1] = v.y; xf[4*i+2] = v.z; xf[4*i+3] = v.w;
    }

    float4 acc[8];
    #pragma unroll
    for (int r = 0; r < 8; ++r) { acc[r].x = 0.f; acc[r].y = 0.f; acc[r].z = 0.f; acc[r].w = 0.f; }

    // d in 4 chunks of 16; weights (4ch x 16d = 64 regs) live for one chunk only
    #pragma unroll 1
    for (int dc = 0; dc < 4; ++dc) {
        float4 wq[4][4];
        #pragma unroll
        for (int c = 0; c < 4; ++c) {
            const float4* wp = (const float4*)(Wd + (size_t)(mbase + c) * kD + dc * 16);
            wq[c][0] = wp[0]; wq[c][1] = wp[1]; wq[c][2] = wp[2]; wq[c][3] = wp[3];
        }
        #pragma unroll
        for (int r8 = 0; r8 < 8; ++r8) {
            const int srcl = 4 * (rowg * 8 + r8) + dc;   // lane holding this row's d-chunk
            float xv[16];
            #pragma unroll
            for (int j = 0; j < 16; ++j)
                xv[j] = rl(xf[j], srcl);                 // x[row, 16dc+j]
            acc[r8].x += dot16(xv, wq[0]);
            acc[r8].y += dot16(xv, wq[1]);
            acc[r8].z += dot16(xv, wq[2]);
            acc[r8].w += dot16(xv, wq[3]);
        }
    }

    const float4 bias = *(const float4*)(bd + mbase);
    size_t obase = (size_t)b * kRows * kDM
                 + (size_t)(kD * kNW + t0 + rowg * 8) * kDM + mbase;
    #pragma unroll
    for (int r8 = 0; r8 < 8; ++r8) {
        f32x4 o = {acc[r8].x + bias.x, acc[r8].y + bias.y,
                   acc[r8].z + bias.z, acc[r8].w + bias.w};
        *(f32x4*)(out + obase + (size_t)r8 * kDM) = o;
    }
}

} // namespace

extern "C" void kernel_launch(void* const* d_in, const int* in_sizes, int n_in,
                              void* d_out, int out_size, void* d_ws, size_t ws_size,
                              hipStream_t stream) {
    const float* x  = (const float*)d_in[0];
    const float* Wt = (const float*)d_in[1];
    const float* bt = (const float*)d_in[2];
    const float* Wd = (const float*)d_in[3];
    const float* bd = (const float*)d_in[4];
    float* out = (float*)d_out;

    hipLaunchKernelGGL(temporal_k, dim3(kB * kD),      dim3(256), 0, stream, x, Wt, bt, out);
    hipLaunchKernelGGL(feature_k,  dim3(kB * (kT/16)), dim3(256), 0, stream, x, Wd, bd, out);
}

// Round 9
// 88.473 us; speedup vs baseline: 3.2338x; 1.0333x over previous
//
#include <hip/hip_runtime.h>
#include <cstddef>
#include <cstdint>

namespace {

constexpr int kB = 32, kT = 512, kD = 64, kP = 16, kNW = 63, kDM = 512;
constexpr int kRows = kD * kNW + kT;     // 4544 output rows per batch

typedef float f32x4  __attribute__((ext_vector_type(4)));
typedef short bf16x8 __attribute__((ext_vector_type(8)));

// ws layout (unsigned short units):
//   Wt frags: [n<32][part<2][lane<64][8]        at 0        (64 KB)
//   Wd frags: [n<32][kc<2][part<2][lane<64][8]  at 32768    (128 KB)
constexpr int kWdOff = 32768;

__device__ __forceinline__ unsigned short bf16_rne(float f) {
    unsigned int u = __float_as_uint(f);
    u += 0x7fffu + ((u >> 16) & 1u);
    return (unsigned short)(u >> 16);
}
__device__ __forceinline__ float bf16_f(unsigned short h) {
    return __uint_as_float(((unsigned int)h) << 16);
}

// Pack Wt / Wd into MFMA A-fragment layout (bf16 hi/lo split).
// A-frag for 16x16x32: lane holds row (lane&15), k = 8*(lane>>4)+j.
__global__ __launch_bounds__(256)
void prep_k(const float* __restrict__ Wt, const float* __restrict__ Wd,
            unsigned short* __restrict__ ws)
{
    const int gid = blockIdx.x * 256 + threadIdx.x;
    // Wt: K=16 padded to 32 -> lanes >=32 hold zeros
    for (int e = gid; e < 32 * 64; e += gridDim.x * 256) {
        const int n = e >> 6, l = e & 63;
        unsigned short* dh = ws + ((size_t)(n * 2 + 0) * 64 + l) * 8;
        unsigned short* dl = ws + ((size_t)(n * 2 + 1) * 64 + l) * 8;
        if (l < 32) {
            const int row = 16 * n + (l & 15);
            const int p0  = 8 * (l >> 4);
            #pragma unroll
            for (int j = 0; j < 8; ++j) {
                float f = Wt[row * kP + p0 + j];
                unsigned short h = bf16_rne(f);
                dh[j] = h;
                dl[j] = bf16_rne(f - bf16_f(h));
            }
        } else {
            #pragma unroll
            for (int j = 0; j < 8; ++j) { dh[j] = 0; dl[j] = 0; }
        }
    }
    // Wd: K=64 -> two k-chunks of 32
    for (int e = gid; e < 32 * 2 * 64; e += gridDim.x * 256) {
        const int n = e >> 7, kc = (e >> 6) & 1, l = e & 63;
        const int row = 16 * n + (l & 15);
        const int d0  = 32 * kc + 8 * (l >> 4);
        unsigned short* dh = ws + kWdOff + ((size_t)((n * 2 + kc) * 2 + 0) * 64 + l) * 8;
        unsigned short* dl = ws + kWdOff + ((size_t)((n * 2 + kc) * 2 + 1) * 64 + l) * 8;
        #pragma unroll
        for (int j = 0; j < 8; ++j) {
            float f = Wd[row * kD + d0 + j];
            unsigned short h = bf16_rne(f);
            dh[j] = h;
            dl[j] = bf16_rne(f - bf16_f(h));
        }
    }
}

// ---- temporal: out[b, d*63+w, ch] = sum_p x[b,8w+p,d]*Wt[ch,p] + bt[ch]
// Per block (b,d): C(64x512) = patches(64x16, padded) . Wt^T, via MFMA.
// Wave 'wave' owns w-tile rows 16*wave..16*wave+15 (row 63 masked off).
__global__ __launch_bounds__(256)
void temporal_k(const float* __restrict__ x, const unsigned short* __restrict__ ws,
                const float* __restrict__ bt, float* __restrict__ out)
{
    __shared__ __align__(16) unsigned short hi_s[640];
    __shared__ __align__(16) unsigned short lo_s[640];
    const int tid = threadIdx.x, lane = tid & 63, wave = tid >> 6;
    const int b = blockIdx.x >> 6, d = blockIdx.x & (kD - 1);

    // stage the x column as bf16 hi/lo (exact split: hi + lo ~ fp32)
    #pragma unroll
    for (int i = 0; i < 2; ++i) {
        const int t = tid + 256 * i;
        const float f = x[(b * kT + t) * kD + d];
        const unsigned short h = bf16_rne(f);
        hi_s[t] = h;
        lo_s[t] = bf16_rne(f - bf16_f(h));
    }
    if (tid < 128) { hi_s[512 + tid] = 0; lo_s[512 + tid] = 0; }   // pad (avoid NaN garbage)
    __syncthreads();

    // B-frag (patches^T): lane holds col (lane&15)=w-sub, k = 8*(lane>>4)+j (k>=16 hits pad)
    const int toff = 128 * wave + 8 * (lane & 15) + 8 * (lane >> 4);
    const bf16x8 Bh = *(const bf16x8*)(hi_s + toff);
    const bf16x8 Bl = *(const bf16x8*)(lo_s + toff);

    const int w      = 16 * wave + (lane & 15);   // D col -> output row
    const bool valid = (w < kNW);
    const int chsub  = 4 * (lane >> 4);           // D rows -> 4 consecutive channels
    float* obase = out + (size_t)b * kRows * kDM + (size_t)(d * kNW + w) * kDM + chsub;

    for (int n = 0; n < 32; ++n) {                // 32 channel tiles of 16
        const bf16x8 Ah = *(const bf16x8*)(ws + ((n * 2 + 0) * 64 + lane) * 8);
        const bf16x8 Al = *(const bf16x8*)(ws + ((n * 2 + 1) * 64 + lane) * 8);
        f32x4 acc = {0.f, 0.f, 0.f, 0.f};
        acc = __builtin_amdgcn_mfma_f32_16x16x32_bf16(Ah, Bh, acc, 0, 0, 0);
        acc = __builtin_amdgcn_mfma_f32_16x16x32_bf16(Al, Bh, acc, 0, 0, 0);
        acc = __builtin_amdgcn_mfma_f32_16x16x32_bf16(Ah, Bl, acc, 0, 0, 0);
        const f32x4 bias = *(const f32x4*)(bt + 16 * n + chsub);
        const f32x4 o = acc + bias;
        if (valid) *(f32x4*)(obase + 16 * n) = o;
    }
}

// ---- feature: out[b, 4032+t, ch] = sum_d x[b,t,d]*Wd[ch,d] + bd[ch]
// Per block (b, 16-row t-tile): C(16x512) = x_tile(16x64) . Wd^T, via MFMA.
// Wave owns 8 channel tiles (128 channels).
__global__ __launch_bounds__(256)
void feature_k(const float* __restrict__ x, const unsigned short* __restrict__ ws,
               const float* __restrict__ bd, float* __restrict__ out)
{
    const int tid = threadIdx.x, lane = tid & 63, wave = tid >> 6;
    const int b = blockIdx.x >> 5, tc = blockIdx.x & 31;
    const int t  = tc * 16 + (lane & 15);
    const int d0 = 8 * (lane >> 4);

    // B-frag (x^T): lane holds col (lane&15)=t-sub, k=d (two 32-chunks), hi/lo split
    const float* xrow = x + ((size_t)b * kT + t) * kD;
    bf16x8 Bh[2], Bl[2];
    #pragma unroll
    for (int kc = 0; kc < 2; ++kc) {
        #pragma unroll
        for (int j = 0; j < 8; ++j) {
            const float f = xrow[32 * kc + d0 + j];
            const unsigned short h = bf16_rne(f);
            Bh[kc][j] = (short)h;
            Bl[kc][j] = (short)bf16_rne(f - bf16_f(h));
        }
    }

    const int chsub = 4 * (lane >> 4);
    float* obase = out + (size_t)b * kRows * kDM + (size_t)(kD * kNW + t) * kDM + chsub;
    const unsigned short* wsd = ws + kWdOff;

    for (int nn = 0; nn < 8; ++nn) {
        const int n = 8 * wave + nn;
        const bf16x8 Ah0 = *(const bf16x8*)(wsd + (((n * 2 + 0) * 2 + 0) * 64 + lane) * 8);
        const bf16x8 Al0 = *(const bf16x8*)(wsd + (((n * 2 + 0) * 2 + 1) * 64 + lane) * 8);
        const bf16x8 Ah1 = *(const bf16x8*)(wsd + (((n * 2 + 1) * 2 + 0) * 64 + lane) * 8);
        const bf16x8 Al1 = *(const bf16x8*)(wsd + (((n * 2 + 1) * 2 + 1) * 64 + lane) * 8);
        f32x4 acc = {0.f, 0.f, 0.f, 0.f};
        acc = __builtin_amdgcn_mfma_f32_16x16x32_bf16(Ah0, Bh[0], acc, 0, 0, 0);
        acc = __builtin_amdgcn_mfma_f32_16x16x32_bf16(Al0, Bh[0], acc, 0, 0, 0);
        acc = __builtin_amdgcn_mfma_f32_16x16x32_bf16(Ah0, Bl[0], acc, 0, 0, 0);
        acc = __builtin_amdgcn_mfma_f32_16x16x32_bf16(Ah1, Bh[1], acc, 0, 0, 0);
        acc = __builtin_amdgcn_mfma_f32_16x16x32_bf16(Al1, Bh[1], acc, 0, 0, 0);
        acc = __builtin_amdgcn_mfma_f32_16x16x32_bf16(Ah1, Bl[1], acc, 0, 0, 0);
        const f32x4 bias = *(const f32x4*)(bd + 16 * n + chsub);
        const f32x4 o = acc + bias;
        *(f32x4*)(obase + 16 * n) = o;
    }
}

} // namespace

extern "C" void kernel_launch(void* const* d_in, const int* in_sizes, int n_in,
                              void* d_out, int out_size, void* d_ws, size_t ws_size,
                              hipStream_t stream) {
    const float* x  = (const float*)d_in[0];
    const float* Wt = (const float*)d_in[1];
    const float* bt = (const float*)d_in[2];
    const float* Wd = (const float*)d_in[3];
    const float* bd = (const float*)d_in[4];
    float* out = (float*)d_out;
    unsigned short* ws = (unsigned short*)d_ws;   // needs 192 KB

    hipLaunchKernelGGL(prep_k,     dim3(8),    dim3(256), 0, stream, Wt, Wd, ws);
    hipLaunchKernelGGL(temporal_k, dim3(kB * kD),      dim3(256), 0, stream, x, ws, bt, out);
    hipLaunchKernelGGL(feature_k,  dim3(kB * (kT/16)), dim3(256), 0, stream, x, ws, bd, out);
}

// Round 10
// 68.978 us; speedup vs baseline: 4.1477x; 1.2826x over previous
//
#include <hip/hip_runtime.h>
#include <cstddef>
#include <cstdint>

namespace {

constexpr int kB = 32, kT = 512, kD = 64, kP = 16, kNW = 63, kDM = 512;
constexpr int kRows = kD * kNW + kT;     // 4544 output rows per batch
constexpr int kSS = 516;                 // slab row stride (floats), +4 pad

typedef float f32x4  __attribute__((ext_vector_type(4)));
typedef short bf16x8 __attribute__((ext_vector_type(8)));

// ws layout (unsigned short units):
//   Wt frags: [n<32][part<2][lane<64][8]        at 0        (64 KB)
//   Wd frags: [n<32][kc<2][part<2][lane<64][8]  at 32768    (128 KB)
constexpr int kWdOff = 32768;

__device__ __forceinline__ unsigned short bf16_rne(float f) {
    unsigned int u = __float_as_uint(f);
    u += 0x7fffu + ((u >> 16) & 1u);
    return (unsigned short)(u >> 16);
}
__device__ __forceinline__ float bf16_f(unsigned short h) {
    return __uint_as_float(((unsigned int)h) << 16);
}

__global__ __launch_bounds__(256)
void prep_k(const float* __restrict__ Wt, const float* __restrict__ Wd,
            unsigned short* __restrict__ ws)
{
    const int gid = blockIdx.x * 256 + threadIdx.x;
    for (int e = gid; e < 32 * 64; e += gridDim.x * 256) {
        const int n = e >> 6, l = e & 63;
        unsigned short* dh = ws + ((size_t)(n * 2 + 0) * 64 + l) * 8;
        unsigned short* dl = ws + ((size_t)(n * 2 + 1) * 64 + l) * 8;
        if (l < 32) {
            const int row = 16 * n + (l & 15);
            const int p0  = 8 * (l >> 4);
            #pragma unroll
            for (int j = 0; j < 8; ++j) {
                float f = Wt[row * kP + p0 + j];
                unsigned short h = bf16_rne(f);
                dh[j] = h;
                dl[j] = bf16_rne(f - bf16_f(h));
            }
        } else {
            #pragma unroll
            for (int j = 0; j < 8; ++j) { dh[j] = 0; dl[j] = 0; }
        }
    }
    for (int e = gid; e < 32 * 2 * 64; e += gridDim.x * 256) {
        const int n = e >> 7, kc = (e >> 6) & 1, l = e & 63;
        const int row = 16 * n + (l & 15);
        const int d0  = 32 * kc + 8 * (l >> 4);
        unsigned short* dh = ws + kWdOff + ((size_t)((n * 2 + kc) * 2 + 0) * 64 + l) * 8;
        unsigned short* dl = ws + kWdOff + ((size_t)((n * 2 + kc) * 2 + 1) * 64 + l) * 8;
        #pragma unroll
        for (int j = 0; j < 8; ++j) {
            float f = Wd[row * kD + d0 + j];
            unsigned short h = bf16_rne(f);
            dh[j] = h;
            dl[j] = bf16_rne(f - bf16_f(h));
        }
    }
}

// ---- temporal: out[b, d*63+w, ch] = sum_p x[b,8w+p,d]*Wt[ch,p] + bt[ch]
// MFMA as R9, but results staged in an LDS slab and stored as contiguous
// 1KB-per-instruction streams (fill-kernel-style write pattern).
__global__ __launch_bounds__(256)
void temporal_k(const float* __restrict__ x, const unsigned short* __restrict__ ws,
                const float* __restrict__ bt, float* __restrict__ out)
{
    __shared__ __align__(16) unsigned short hi_s[640];
    __shared__ __align__(16) unsigned short lo_s[640];
    __shared__ __align__(16) float slab[16 * kSS];   // 33 KB
    const int tid = threadIdx.x, lane = tid & 63, wave = tid >> 6;
    const int b = blockIdx.x >> 6, d = blockIdx.x & (kD - 1);

    #pragma unroll
    for (int i = 0; i < 2; ++i) {
        const int t = tid + 256 * i;
        const float f = x[(b * kT + t) * kD + d];
        const unsigned short h = bf16_rne(f);
        hi_s[t] = h;
        lo_s[t] = bf16_rne(f - bf16_f(h));
    }
    if (tid < 128) { hi_s[512 + tid] = 0; lo_s[512 + tid] = 0; }
    __syncthreads();

    // hoist this wave's 8 n-tiles of A-frags (channels 128*wave..+127)
    bf16x8 Ah[8], Al[8];
    #pragma unroll
    for (int i = 0; i < 8; ++i) {
        const int n = 8 * wave + i;
        Ah[i] = *(const bf16x8*)(ws + ((n * 2 + 0) * 64 + lane) * 8);
        Al[i] = *(const bf16x8*)(ws + ((n * 2 + 1) * 64 + lane) * 8);
    }

    const int chsub  = 4 * (lane >> 4);
    const int wrbase = (lane & 15) * kSS + chsub;    // slab row = w-sub
    float* orow = out + (size_t)b * kRows * kDM + (size_t)(d * kNW) * kDM;

    for (int g = 0; g < 4; ++g) {
        // B-frag for w-group g (w = 16g + (lane&15)); pad region is zeroed
        const int toff = 128 * g + 8 * (lane & 15) + 8 * (lane >> 4);
        const bf16x8 Bh = *(const bf16x8*)(hi_s + toff);
        const bf16x8 Bl = *(const bf16x8*)(lo_s + toff);

        #pragma unroll
        for (int i = 0; i < 8; ++i) {
            const int n = 8 * wave + i;
            f32x4 acc = {0.f, 0.f, 0.f, 0.f};
            acc = __builtin_amdgcn_mfma_f32_16x16x32_bf16(Ah[i], Bh, acc, 0, 0, 0);
            acc = __builtin_amdgcn_mfma_f32_16x16x32_bf16(Al[i], Bh, acc, 0, 0, 0);
            acc = __builtin_amdgcn_mfma_f32_16x16x32_bf16(Ah[i], Bl, acc, 0, 0, 0);
            const f32x4 bias = *(const f32x4*)(bt + 16 * n + chsub);
            *(f32x4*)(slab + wrbase + 16 * n) = acc + bias;
        }
        __syncthreads();

        // contiguous sweep: wave owns slab rows 4*wave..+3; 1 KB per store instr
        #pragma unroll
        for (int r = 0; r < 4; ++r) {
            const int srow = 4 * wave + r;
            const int wrow = 16 * g + srow;
            if (wrow < kNW) {
                #pragma unroll
                for (int h = 0; h < 2; ++h) {
                    const f32x4 v = *(const f32x4*)(slab + srow * kSS + h * 256 + lane * 4);
                    *(f32x4*)(orow + (size_t)wrow * kDM + h * 256 + lane * 4) = v;
                }
            }
        }
        __syncthreads();
    }
}

// ---- feature: out[b, 4032+t, ch] = sum_d x[b,t,d]*Wd[ch,d] + bd[ch]
__global__ __launch_bounds__(256)
void feature_k(const float* __restrict__ x, const unsigned short* __restrict__ ws,
               const float* __restrict__ bd, float* __restrict__ out)
{
    __shared__ __align__(16) float slab[16 * kSS];   // 33 KB
    const int tid = threadIdx.x, lane = tid & 63, wave = tid >> 6;
    const int b = blockIdx.x >> 5, tc = blockIdx.x & 31;
    const int t  = tc * 16 + (lane & 15);
    const int d0 = 8 * (lane >> 4);

    const float* xrow = x + ((size_t)b * kT + t) * kD;
    bf16x8 Bh[2], Bl[2];
    #pragma unroll
    for (int kc = 0; kc < 2; ++kc) {
        #pragma unroll
        for (int j = 0; j < 8; ++j) {
            const float f = xrow[32 * kc + d0 + j];
            const unsigned short h = bf16_rne(f);
            Bh[kc][j] = (short)h;
            Bl[kc][j] = (short)bf16_rne(f - bf16_f(h));
        }
    }

    const int chsub  = 4 * (lane >> 4);
    const int wrbase = (lane & 15) * kSS + chsub;    // slab row = t-sub
    const unsigned short* wsd = ws + kWdOff;

    #pragma unroll
    for (int i = 0; i < 8; ++i) {
        const int n = 8 * wave + i;
        const bf16x8 Ah0 = *(const bf16x8*)(wsd + (((n * 2 + 0) * 2 + 0) * 64 + lane) * 8);
        const bf16x8 Al0 = *(const bf16x8*)(wsd + (((n * 2 + 0) * 2 + 1) * 64 + lane) * 8);
        const bf16x8 Ah1 = *(const bf16x8*)(wsd + (((n * 2 + 1) * 2 + 0) * 64 + lane) * 8);
        const bf16x8 Al1 = *(const bf16x8*)(wsd + (((n * 2 + 1) * 2 + 1) * 64 + lane) * 8);
        f32x4 acc = {0.f, 0.f, 0.f, 0.f};
        acc = __builtin_amdgcn_mfma_f32_16x16x32_bf16(Ah0, Bh[0], acc, 0, 0, 0);
        acc = __builtin_amdgcn_mfma_f32_16x16x32_bf16(Al0, Bh[0], acc, 0, 0, 0);
        acc = __builtin_amdgcn_mfma_f32_16x16x32_bf16(Ah0, Bl[0], acc, 0, 0, 0);
        acc = __builtin_amdgcn_mfma_f32_16x16x32_bf16(Ah1, Bh[1], acc, 0, 0, 0);
        acc = __builtin_amdgcn_mfma_f32_16x16x32_bf16(Al1, Bh[1], acc, 0, 0, 0);
        acc = __builtin_amdgcn_mfma_f32_16x16x32_bf16(Ah1, Bl[1], acc, 0, 0, 0);
        const f32x4 bias = *(const f32x4*)(bd + 16 * n + chsub);
        *(f32x4*)(slab + wrbase + 16 * n) = acc + bias;
    }
    __syncthreads();

    float* orows = out + (size_t)b * kRows * kDM + (size_t)(kD * kNW + tc * 16) * kDM;
    #pragma unroll
    for (int r = 0; r < 4; ++r) {
        const int srow = 4 * wave + r;
        #pragma unroll
        for (int h = 0; h < 2; ++h) {
            const f32x4 v = *(const f32x4*)(slab + srow * kSS + h * 256 + lane * 4);
            *(f32x4*)(orows + (size_t)srow * kDM + h * 256 + lane * 4) = v;
        }
    }
}

} // namespace

extern "C" void kernel_launch(void* const* d_in, const int* in_sizes, int n_in,
                              void* d_out, int out_size, void* d_ws, size_t ws_size,
                              hipStream_t stream) {
    const float* x  = (const float*)d_in[0];
    const float* Wt = (const float*)d_in[1];
    const float* bt = (const float*)d_in[2];
    const float* Wd = (const float*)d_in[3];
    const float* bd = (const float*)d_in[4];
    float* out = (float*)d_out;
    unsigned short* ws = (unsigned short*)d_ws;   // needs 192 KB

    hipLaunchKernelGGL(prep_k,     dim3(8),            dim3(256), 0, stream, Wt, Wd, ws);
    hipLaunchKernelGGL(temporal_k, dim3(kB * kD),      dim3(256), 0, stream, x, ws, bt, out);
    hipLaunchKernelGGL(feature_k,  dim3(kB * (kT/16)), dim3(256), 0, stream, x, ws, bd, out);
}

// Round 11
// 64.521 us; speedup vs baseline: 4.4342x; 1.0691x over previous
//
#include <hip/hip_runtime.h>
#include <cstddef>
#include <cstdint>

namespace {

constexpr int kB = 32, kT = 512, kD = 64, kP = 16, kNW = 63, kDM = 512;
constexpr int kRows = kD * kNW + kT;     // 4544 output rows per batch
constexpr int kSS = 516;                 // slab row stride (floats), +4 pad
constexpr int kNBF = kB * (kT / 16);     // 1024 feature blocks (first)
constexpr int kNBT = kB * kD;            // 2048 temporal blocks

typedef float f32x4  __attribute__((ext_vector_type(4)));
typedef short bf16x8 __attribute__((ext_vector_type(8)));

// ws layout (unsigned short units):
//   Wt frags: [n<32][part<2][lane<64][8]        at 0        (64 KB)
//   Wd frags: [n<32][kc<2][part<2][lane<64][8]  at 32768    (128 KB)
constexpr int kWdOff = 32768;

__device__ __forceinline__ unsigned short bf16_rne(float f) {
    unsigned int u = __float_as_uint(f);
    u += 0x7fffu + ((u >> 16) & 1u);
    return (unsigned short)(u >> 16);
}
__device__ __forceinline__ float bf16_f(unsigned short h) {
    return __uint_as_float(((unsigned int)h) << 16);
}

__global__ __launch_bounds__(256)
void prep_k(const float* __restrict__ Wt, const float* __restrict__ Wd,
            unsigned short* __restrict__ ws)
{
    const int gid = blockIdx.x * 256 + threadIdx.x;
    for (int e = gid; e < 32 * 64; e += gridDim.x * 256) {
        const int n = e >> 6, l = e & 63;
        unsigned short* dh = ws + ((size_t)(n * 2 + 0) * 64 + l) * 8;
        unsigned short* dl = ws + ((size_t)(n * 2 + 1) * 64 + l) * 8;
        if (l < 32) {
            const int row = 16 * n + (l & 15);
            const int p0  = 8 * (l >> 4);
            #pragma unroll
            for (int j = 0; j < 8; ++j) {
                float f = Wt[row * kP + p0 + j];
                unsigned short h = bf16_rne(f);
                dh[j] = h;
                dl[j] = bf16_rne(f - bf16_f(h));
            }
        } else {
            #pragma unroll
            for (int j = 0; j < 8; ++j) { dh[j] = 0; dl[j] = 0; }
        }
    }
    for (int e = gid; e < 32 * 2 * 64; e += gridDim.x * 256) {
        const int n = e >> 7, kc = (e >> 6) & 1, l = e & 63;
        const int row = 16 * n + (l & 15);
        const int d0  = 32 * kc + 8 * (l >> 4);
        unsigned short* dh = ws + kWdOff + ((size_t)((n * 2 + kc) * 2 + 0) * 64 + l) * 8;
        unsigned short* dl = ws + kWdOff + ((size_t)((n * 2 + kc) * 2 + 1) * 64 + l) * 8;
        #pragma unroll
        for (int j = 0; j < 8; ++j) {
            float f = Wd[row * kD + d0 + j];
            unsigned short h = bf16_rne(f);
            dh[j] = h;
            dl[j] = bf16_rne(f - bf16_f(h));
        }
    }
}

// One kernel, two block types. Feature blocks first (their 33 MB of writes
// overlap temporal's ramp). Bias is added in the sweep from 2 reg-resident
// f32x4 per thread (loaded once per block) instead of 8 VMEM loads per
// MFMA group.
__global__ __launch_bounds__(256)
void main_k(const float* __restrict__ x, const unsigned short* __restrict__ ws,
            const float* __restrict__ bt, const float* __restrict__ bd,
            float* __restrict__ out)
{
    __shared__ __align__(16) float slab[16 * kSS];          // 33 KB
    __shared__ __align__(16) unsigned short hi_s[640];
    __shared__ __align__(16) unsigned short lo_s[640];
    const int tid = threadIdx.x, lane = tid & 63, wave = tid >> 6;

    if ((int)blockIdx.x >= kNBF) {
        // ---- temporal: out[b, d*63+w, ch] = sum_p x[b,8w+p,d]*Wt[ch,p] + bt[ch]
        const int blk = blockIdx.x - kNBF;
        const int b = blk >> 6, d = blk & (kD - 1);

        #pragma unroll
        for (int i = 0; i < 2; ++i) {
            const int t = tid + 256 * i;
            const float f = x[(b * kT + t) * kD + d];
            const unsigned short h = bf16_rne(f);
            hi_s[t] = h;
            lo_s[t] = bf16_rne(f - bf16_f(h));
        }
        if (tid < 128) { hi_s[512 + tid] = 0; lo_s[512 + tid] = 0; }
        __syncthreads();

        // this wave's 8 n-tiles of A-frags (channels 128*wave..+127)
        bf16x8 Ah[8], Al[8];
        #pragma unroll
        for (int i = 0; i < 8; ++i) {
            const int n = 8 * wave + i;
            Ah[i] = *(const bf16x8*)(ws + ((n * 2 + 0) * 64 + lane) * 8);
            Al[i] = *(const bf16x8*)(ws + ((n * 2 + 1) * 64 + lane) * 8);
        }

        // sweep bias: thread covers cols {h*256 + lane*4} for h=0,1
        f32x4 biasw[2];
        biasw[0] = *(const f32x4*)(bt + lane * 4);
        biasw[1] = *(const f32x4*)(bt + 256 + lane * 4);

        const int chsub  = 4 * (lane >> 4);
        const int wrbase = (lane & 15) * kSS + chsub;    // slab row = w-sub
        float* orow = out + (size_t)b * kRows * kDM + (size_t)(d * kNW) * kDM;

        for (int g = 0; g < 4; ++g) {
            const int toff = 128 * g + 8 * (lane & 15) + 8 * (lane >> 4);
            const bf16x8 Bh = *(const bf16x8*)(hi_s + toff);
            const bf16x8 Bl = *(const bf16x8*)(lo_s + toff);

            #pragma unroll
            for (int i = 0; i < 8; ++i) {
                const int n = 8 * wave + i;
                f32x4 acc = {0.f, 0.f, 0.f, 0.f};
                acc = __builtin_amdgcn_mfma_f32_16x16x32_bf16(Ah[i], Bh, acc, 0, 0, 0);
                acc = __builtin_amdgcn_mfma_f32_16x16x32_bf16(Al[i], Bh, acc, 0, 0, 0);
                acc = __builtin_amdgcn_mfma_f32_16x16x32_bf16(Ah[i], Bl, acc, 0, 0, 0);
                *(f32x4*)(slab + wrbase + 16 * n) = acc;
            }
            __syncthreads();

            // contiguous sweep: wave owns slab rows 4*wave..+3; 1 KB / instr
            #pragma unroll
            for (int r = 0; r < 4; ++r) {
                const int srow = 4 * wave + r;
                const int wrow = 16 * g + srow;
                if (wrow < kNW) {
                    #pragma unroll
                    for (int h = 0; h < 2; ++h) {
                        const f32x4 v = *(const f32x4*)(slab + srow * kSS + h * 256 + lane * 4);
                        *(f32x4*)(orow + (size_t)wrow * kDM + h * 256 + lane * 4) = v + biasw[h];
                    }
                }
            }
            __syncthreads();
        }
    } else {
        // ---- feature: out[b, 4032+t, ch] = sum_d x[b,t,d]*Wd[ch,d] + bd[ch]
        const int blk = blockIdx.x;
        const int b = blk >> 5, tc = blk & 31;
        const int t  = tc * 16 + (lane & 15);
        const int d0 = 8 * (lane >> 4);

        const float* xrow = x + ((size_t)b * kT + t) * kD;
        bf16x8 Bh[2], Bl[2];
        #pragma unroll
        for (int kc = 0; kc < 2; ++kc) {
            #pragma unroll
            for (int j = 0; j < 8; ++j) {
                const float f = xrow[32 * kc + d0 + j];
                const unsigned short h = bf16_rne(f);
                Bh[kc][j] = (short)h;
                Bl[kc][j] = (short)bf16_rne(f - bf16_f(h));
            }
        }

        f32x4 biasw[2];
        biasw[0] = *(const f32x4*)(bd + lane * 4);
        biasw[1] = *(const f32x4*)(bd + 256 + lane * 4);

        const int chsub  = 4 * (lane >> 4);
        const int wrbase = (lane & 15) * kSS + chsub;    // slab row = t-sub
        const unsigned short* wsd = ws + kWdOff;

        #pragma unroll
        for (int i = 0; i < 8; ++i) {
            const int n = 8 * wave + i;
            const bf16x8 Ah0 = *(const bf16x8*)(wsd + (((n * 2 + 0) * 2 + 0) * 64 + lane) * 8);
            const bf16x8 Al0 = *(const bf16x8*)(wsd + (((n * 2 + 0) * 2 + 1) * 64 + lane) * 8);
            const bf16x8 Ah1 = *(const bf16x8*)(wsd + (((n * 2 + 1) * 2 + 0) * 64 + lane) * 8);
            const bf16x8 Al1 = *(const bf16x8*)(wsd + (((n * 2 + 1) * 2 + 1) * 64 + lane) * 8);
            f32x4 acc = {0.f, 0.f, 0.f, 0.f};
            acc = __builtin_amdgcn_mfma_f32_16x16x32_bf16(Ah0, Bh[0], acc, 0, 0, 0);
            acc = __builtin_amdgcn_mfma_f32_16x16x32_bf16(Al0, Bh[0], acc, 0, 0, 0);
            acc = __builtin_amdgcn_mfma_f32_16x16x32_bf16(Ah0, Bl[0], acc, 0, 0, 0);
            acc = __builtin_amdgcn_mfma_f32_16x16x32_bf16(Ah1, Bh[1], acc, 0, 0, 0);
            acc = __builtin_amdgcn_mfma_f32_16x16x32_bf16(Al1, Bh[1], acc, 0, 0, 0);
            acc = __builtin_amdgcn_mfma_f32_16x16x32_bf16(Ah1, Bl[1], acc, 0, 0, 0);
            *(f32x4*)(slab + wrbase + 16 * n) = acc;
        }
        __syncthreads();

        float* orows = out + (size_t)b * kRows * kDM + (size_t)(kD * kNW + tc * 16) * kDM;
        #pragma unroll
        for (int r = 0; r < 4; ++r) {
            const int srow = 4 * wave + r;
            #pragma unroll
            for (int h = 0; h < 2; ++h) {
                const f32x4 v = *(const f32x4*)(slab + srow * kSS + h * 256 + lane * 4);
                *(f32x4*)(orows + (size_t)srow * kDM + h * 256 + lane * 4) = v + biasw[h];
            }
        }
    }
}

} // namespace

extern "C" void kernel_launch(void* const* d_in, const int* in_sizes, int n_in,
                              void* d_out, int out_size, void* d_ws, size_t ws_size,
                              hipStream_t stream) {
    const float* x  = (const float*)d_in[0];
    const float* Wt = (const float*)d_in[1];
    const float* bt = (const float*)d_in[2];
    const float* Wd = (const float*)d_in[3];
    const float* bd = (const float*)d_in[4];
    float* out = (float*)d_out;
    unsigned short* ws = (unsigned short*)d_ws;   // needs 192 KB

    hipLaunchKernelGGL(prep_k, dim3(16),           dim3(256), 0, stream, Wt, Wd, ws);
    hipLaunchKernelGGL(main_k, dim3(kNBF + kNBT),  dim3(256), 0, stream, x, ws, bt, bd, out);
}